// Round 1
// baseline (220.624 us; speedup 1.0000x reference)
//
#include <hip/hip_runtime.h>

#define N_NODES 2048
#define N_EDGES 65536
#define NV 6
#define C 32

// ---------------------------------------------------------------------------
// ws layout (floats):
//   [0, N)            : cnt   (in-degree per node, fp32)   -- zeroed
//   [N, N+3*N*C)      : sum1, sum2, sum3 (scatter-add)     -- zeroed
//   [N+3NC, N+6NC)    : h1, h2, h3 (node features)         -- fully overwritten
// ---------------------------------------------------------------------------

__global__ void count_kernel(const int* __restrict__ dst, float* __restrict__ cnt) {
    int e = blockIdx.x * blockDim.x + threadIdx.x;
    if (e < N_EDGES) atomicAdd(&cnt[dst[e]], 1.0f);
}

// Layer 1: in_c = 1. One thread per (edge, o).
__global__ void edge1_kernel(const float* __restrict__ x,
                             const float* __restrict__ ea,
                             const int* __restrict__ src,
                             const int* __restrict__ dst,
                             const float* __restrict__ W1,
                             const float* __restrict__ b1,
                             float* __restrict__ sum1) {
    int t = blockIdx.x * blockDim.x + threadIdx.x;
    int e = t >> 5, o = t & 31;
    if (e >= N_EDGES) return;
    const float* eap = ea + e * NV;
    float w = b1[o];
#pragma unroll
    for (int v = 0; v < NV; v++) w += eap[v] * W1[v * C + o];
    w = fmaxf(w, 0.0f);
    atomicAdd(&sum1[dst[e] * C + o], x[src[e]] * w);
}

// Finalize a layer: h_out = relu(sum/max(cnt,1) + h_prev @ root + bias)
template <int IN_C>
__global__ void node_kernel(const float* __restrict__ sum,
                            const float* __restrict__ cnt,
                            const float* __restrict__ hprev,
                            const float* __restrict__ root,  // [IN_C, C]
                            const float* __restrict__ bias,  // [C]
                            float* __restrict__ hout) {
    int t = blockIdx.x * blockDim.x + threadIdx.x;  // N*C threads
    int n = t >> 5, o = t & 31;
    float inv = 1.0f / fmaxf(cnt[n], 1.0f);
    float acc = sum[t] * inv + bias[o];
#pragma unroll
    for (int i = 0; i < IN_C; i++) acc += hprev[n * IN_C + i] * root[i * C + o];
    hout[t] = fmaxf(acc, 0.0f);
}

// Layers 2/3: in_c = out_c = 32. One wave per edge.
// lane l: o = l&31, i-range = [ (l>>5)*16, +16 ).
// W[NV][1024] + b[1024] in LDS (28 KB). LDS reads: o spans banks 0..31,
// half-waves 2-way alias (free). h[src] loaded coalesced, spread via shfl.
__global__ __launch_bounds__(256) void edge23_kernel(
    const float* __restrict__ hprev,   // [N, 32]
    const float* __restrict__ ea,      // [E, 6]
    const int* __restrict__ src,
    const int* __restrict__ dst,
    const float* __restrict__ W,       // [NV, 1024]
    const float* __restrict__ b,       // [1024]
    float* __restrict__ sumout)        // [N, 32]
{
    __shared__ float Wlds[NV * 1024];
    __shared__ float blds[1024];
    for (int i = threadIdx.x; i < NV * 1024; i += 256) Wlds[i] = W[i];
    for (int i = threadIdx.x; i < 1024; i += 256) blds[i] = b[i];
    __syncthreads();

    const int lane = threadIdx.x & 63;
    const int o = lane & 31;
    const int i0 = (lane >> 5) * 16;
    const int wid = (blockIdx.x * 256 + threadIdx.x) >> 6;
    const int nwaves = (gridDim.x * 256) >> 6;

    for (int e = wid; e < N_EDGES; e += nwaves) {
        const int s = src[e];
        const int d = dst[e];
        const float* eap = ea + e * NV;
        const float ea0 = eap[0], ea1 = eap[1], ea2 = eap[2];
        const float ea3 = eap[3], ea4 = eap[4], ea5 = eap[5];
        const float hval = hprev[s * C + o];  // lanes hold h_src[0..31] (x2)
        float partial = 0.0f;
#pragma unroll
        for (int j = 0; j < 16; j++) {
            const int i = i0 + j;
            const float hv = __shfl(hval, i);      // h_src[i]
            const int idx = i * C + o;
            float w = blds[idx];
            w += ea0 * Wlds[0 * 1024 + idx];
            w += ea1 * Wlds[1 * 1024 + idx];
            w += ea2 * Wlds[2 * 1024 + idx];
            w += ea3 * Wlds[3 * 1024 + idx];
            w += ea4 * Wlds[4 * 1024 + idx];
            w += ea5 * Wlds[5 * 1024 + idx];
            w = fmaxf(w, 0.0f);
            partial += hv * w;
        }
        const float other = __shfl_down(partial, 32);
        if (lane < 32) atomicAdd(&sumout[d * C + o], partial + other);
    }
}

// CBT: out[i,j] = sum_k |h[i,k]-h[j,k]|. 64-thread blocks, 64x64 tiles.
// lane -> j (coalesced stores); h_j in regs; h_i broadcast from LDS.
__global__ __launch_bounds__(64) void cbt_kernel(const float* __restrict__ h,
                                                 float* __restrict__ out) {
    __shared__ float hj_s[64][33];  // +1 pad: reg-copy read is 2-way (free)
    __shared__ float hi_s[64 * 32]; // uniform reads -> broadcast
    const int lane = threadIdx.x;
    const int j0 = blockIdx.x * 64;
    const int i0 = blockIdx.y * 64;
    for (int t = lane; t < 64 * 32; t += 64) {
        hj_s[t >> 5][t & 31] = h[j0 * 32 + t];
        hi_s[t] = h[i0 * 32 + t];
    }
    __syncthreads();
    float hj[32];
#pragma unroll
    for (int k = 0; k < 32; k++) hj[k] = hj_s[lane][k];
    const int j = j0 + lane;
    for (int ii = 0; ii < 64; ii++) {
        float acc = 0.0f;
#pragma unroll
        for (int k = 0; k < 32; k++) {
            acc += fabsf(hi_s[ii * 32 + k] - hj[k]);
        }
        out[(size_t)(i0 + ii) * N_NODES + j] = acc;
    }
}

extern "C" void kernel_launch(void* const* d_in, const int* in_sizes, int n_in,
                              void* d_out, int out_size, void* d_ws, size_t ws_size,
                              hipStream_t stream) {
    const float* x         = (const float*)d_in[0];
    const float* edge_attr = (const float*)d_in[1];
    const int*   edge_idx  = (const int*)d_in[2];
    const float* W1 = (const float*)d_in[3];
    const float* b1 = (const float*)d_in[4];
    const float* root1 = (const float*)d_in[5];
    const float* bias1 = (const float*)d_in[6];
    const float* W2 = (const float*)d_in[7];
    const float* b2 = (const float*)d_in[8];
    const float* root2 = (const float*)d_in[9];
    const float* bias2 = (const float*)d_in[10];
    const float* W3 = (const float*)d_in[11];
    const float* b3 = (const float*)d_in[12];
    const float* root3 = (const float*)d_in[13];
    const float* bias3 = (const float*)d_in[14];

    const int* src = edge_idx;            // row 0
    const int* dst = edge_idx + N_EDGES;  // row 1

    float* ws   = (float*)d_ws;
    float* cnt  = ws;
    float* sum1 = ws + N_NODES;
    float* sum2 = sum1 + N_NODES * C;
    float* sum3 = sum2 + N_NODES * C;
    float* h1   = sum3 + N_NODES * C;
    float* h2   = h1 + N_NODES * C;
    float* h3   = h2 + N_NODES * C;

    // zero cnt + sum1..sum3 (contiguous)
    hipMemsetAsync(d_ws, 0, (size_t)(N_NODES + 3 * N_NODES * C) * sizeof(float), stream);

    count_kernel<<<N_EDGES / 256, 256, 0, stream>>>(dst, cnt);

    // Layer 1
    edge1_kernel<<<(N_EDGES * C) / 256, 256, 0, stream>>>(x, edge_attr, src, dst, W1, b1, sum1);
    node_kernel<1><<<(N_NODES * C) / 256, 256, 0, stream>>>(sum1, cnt, x, root1, bias1, h1);

    // Layer 2
    edge23_kernel<<<2048, 256, 0, stream>>>(h1, edge_attr, src, dst, W2, b2, sum2);
    node_kernel<C><<<(N_NODES * C) / 256, 256, 0, stream>>>(sum2, cnt, h1, root2, bias2, h2);

    // Layer 3
    edge23_kernel<<<2048, 256, 0, stream>>>(h2, edge_attr, src, dst, W3, b3, sum3);
    node_kernel<C><<<(N_NODES * C) / 256, 256, 0, stream>>>(sum3, cnt, h2, root3, bias3, h3);

    // CBT
    cbt_kernel<<<dim3(N_NODES / 64, N_NODES / 64), 64, 0, stream>>>(h3, (float*)d_out);
}

// Round 2
// 173.434 us; speedup vs baseline: 1.2721x; 1.2721x over previous
//
#include <hip/hip_runtime.h>

#define N_NODES 2048
#define N_EDGES 65536
#define NV 6
#define C 32

// ---------------------------------------------------------------------------
// ws layout (floats):
//   [0, N)            : cnt   (in-degree per node, fp32)   -- zeroed
//   [N, N+3*N*C)      : sum1, sum2, sum3 (scatter-add)     -- zeroed
//   [N+3NC, N+6NC)    : h1, h2, h3 (node features)         -- fully overwritten
// ---------------------------------------------------------------------------

// Layer 1 (in_c = 1), with degree count fused in (o==0 lane).
__global__ void edge1_kernel(const float* __restrict__ x,
                             const float* __restrict__ ea,
                             const int* __restrict__ src,
                             const int* __restrict__ dst,
                             const float* __restrict__ W1,
                             const float* __restrict__ b1,
                             float* __restrict__ sum1,
                             float* __restrict__ cnt) {
    int t = blockIdx.x * blockDim.x + threadIdx.x;
    int e = t >> 5, o = t & 31;
    if (e >= N_EDGES) return;
    const float* eap = ea + e * NV;
    float w = b1[o];
#pragma unroll
    for (int v = 0; v < NV; v++) w += eap[v] * W1[v * C + o];
    w = fmaxf(w, 0.0f);
    int d = dst[e];
    atomicAdd(&sum1[d * C + o], x[src[e]] * w);
    if (o == 0) atomicAdd(&cnt[d], 1.0f);
}

// Finalize a layer: h_out = relu(sum/max(cnt,1) + h_prev @ root + bias)
template <int IN_C>
__global__ void node_kernel(const float* __restrict__ sum,
                            const float* __restrict__ cnt,
                            const float* __restrict__ hprev,
                            const float* __restrict__ root,  // [IN_C, C]
                            const float* __restrict__ bias,  // [C]
                            float* __restrict__ hout) {
    int t = blockIdx.x * blockDim.x + threadIdx.x;  // N*C threads
    int n = t >> 5, o = t & 31;
    float inv = 1.0f / fmaxf(cnt[n], 1.0f);
    float acc = sum[t] * inv + bias[o];
#pragma unroll
    for (int i = 0; i < IN_C; i++) acc += hprev[n * IN_C + i] * root[i * C + o];
    hout[t] = fmaxf(acc, 0.0f);
}

// Layers 2/3: one wave processes 4 edges per pass (EPW=4) so every W LDS read
// serves 4 edges. lane l: o = l&31, i-range [ (l>>5)*16, +16 ).
// Wall[7*1024] in LDS (planes 0..5 = W, plane 6 = b): lane reads stride-32 ->
// banks 0..31, half-waves 2-way alias (free, verified 0 conflicts in R0).
// h distribution: per-wave staging hb[i][k] read as broadcast ds_read_b128
// (16 ops / 4 edges instead of 64 ds_bpermute).
__global__ __launch_bounds__(256) void edge23_kernel(
    const float* __restrict__ hprev,   // [N, 32]
    const float* __restrict__ ea,      // [E, 6]
    const int* __restrict__ src,
    const int* __restrict__ dst,
    const float* __restrict__ W,       // [NV, 1024]
    const float* __restrict__ b,       // [1024]
    float* __restrict__ sumout)        // [N, 32]
{
    __shared__ float Wall[7 * 1024];   // 28 KB
    __shared__ float hb[4][32 * 4];    // per-wave h staging: [i][k]
    for (int i = threadIdx.x; i < 6 * 1024; i += 256) Wall[i] = W[i];
    for (int i = threadIdx.x; i < 1024; i += 256) Wall[6 * 1024 + i] = b[i];
    __syncthreads();

    const int lane = threadIdx.x & 63;
    const int o = lane & 31;
    const int i0 = (lane >> 5) * 16;
    const int w = threadIdx.x >> 6;
    const int wid = (blockIdx.x * 256 + threadIdx.x) >> 6;
    const int nwaves = (gridDim.x * 256) >> 6;  // 8192
    float* hbw = &hb[w][0];

    for (int g = wid; g < N_EDGES / 4; g += nwaves) {
        const int e0 = g * 4;
        // edge metadata (wave-uniform addresses; L1/L2 hits)
        int s0 = src[e0 + 0], s1 = src[e0 + 1], s2 = src[e0 + 2], s3 = src[e0 + 3];
        int d0 = dst[e0 + 0], d1 = dst[e0 + 1], d2 = dst[e0 + 2], d3 = dst[e0 + 3];
        const float* eap = ea + (size_t)e0 * NV;
        float ea0[NV], ea1[NV], ea2[NV], ea3[NV];
#pragma unroll
        for (int v = 0; v < NV; v++) {
            ea0[v] = eap[v];
            ea1[v] = eap[NV + v];
            ea2[v] = eap[2 * NV + v];
            ea3[v] = eap[3 * NV + v];
        }
        // lane i (i<32) holds h[s_k][i]; stage as hb[i][k] for b128 broadcast
        float hv0 = hprev[s0 * C + o];
        float hv1 = hprev[s1 * C + o];
        float hv2 = hprev[s2 * C + o];
        float hv3 = hprev[s3 * C + o];
        __builtin_amdgcn_s_waitcnt(0xc07f);  // prior group's hb reads retired
        if (lane < 32) {
            float4 hq = {hv0, hv1, hv2, hv3};
            *(float4*)&hbw[lane * 4] = hq;
        }
        __builtin_amdgcn_s_waitcnt(0xc07f);  // staging visible to own wave

        float acc0 = 0.0f, acc1 = 0.0f, acc2 = 0.0f, acc3 = 0.0f;
#pragma unroll
        for (int j = 0; j < 16; j++) {
            const int idx = (i0 + j) * C + o;
            const float w0 = Wall[0 * 1024 + idx];
            const float w1 = Wall[1 * 1024 + idx];
            const float w2 = Wall[2 * 1024 + idx];
            const float w3 = Wall[3 * 1024 + idx];
            const float w4 = Wall[4 * 1024 + idx];
            const float w5 = Wall[5 * 1024 + idx];
            const float bb = Wall[6 * 1024 + idx];
            const float4 hq = *(const float4*)&hbw[(i0 + j) * 4];
            float t0 = bb + ea0[0] * w0 + ea0[1] * w1 + ea0[2] * w2 + ea0[3] * w3 + ea0[4] * w4 + ea0[5] * w5;
            float t1 = bb + ea1[0] * w0 + ea1[1] * w1 + ea1[2] * w2 + ea1[3] * w3 + ea1[4] * w4 + ea1[5] * w5;
            float t2 = bb + ea2[0] * w0 + ea2[1] * w1 + ea2[2] * w2 + ea2[3] * w3 + ea2[4] * w4 + ea2[5] * w5;
            float t3 = bb + ea3[0] * w0 + ea3[1] * w1 + ea3[2] * w2 + ea3[3] * w3 + ea3[4] * w4 + ea3[5] * w5;
            acc0 += hq.x * fmaxf(t0, 0.0f);
            acc1 += hq.y * fmaxf(t1, 0.0f);
            acc2 += hq.z * fmaxf(t2, 0.0f);
            acc3 += hq.w * fmaxf(t3, 0.0f);
        }
        acc0 += __shfl_down(acc0, 32);
        acc1 += __shfl_down(acc1, 32);
        acc2 += __shfl_down(acc2, 32);
        acc3 += __shfl_down(acc3, 32);
        if (lane < 32) {
            atomicAdd(&sumout[d0 * C + o], acc0);
            atomicAdd(&sumout[d1 * C + o], acc1);
            atomicAdd(&sumout[d2 * C + o], acc2);
            atomicAdd(&sumout[d3 * C + o], acc3);
        }
    }
}

// CBT: out[i,j] = sum_k |h[i,k]-h[j,k]|. 256-thread blocks, 64x64 tiles,
// wave w handles i-rows [w*16, w*16+16). 1024 blocks -> 16 waves/CU.
__global__ __launch_bounds__(256) void cbt_kernel(const float* __restrict__ h,
                                                  float* __restrict__ out) {
    __shared__ float hj_s[64][33];  // lane*33+k -> bank (lane+k)%32, conflict-free
    __shared__ float hi_s[64 * 32]; // uniform reads -> broadcast
    const int lane = threadIdx.x & 63;
    const int w = threadIdx.x >> 6;
    const int j0 = blockIdx.x * 64;
    const int i0 = blockIdx.y * 64;
    for (int t = threadIdx.x; t < 64 * 32; t += 256) {
        hj_s[t >> 5][t & 31] = h[j0 * 32 + t];
        hi_s[t] = h[i0 * 32 + t];
    }
    __syncthreads();
    float hj[32];
#pragma unroll
    for (int k = 0; k < 32; k++) hj[k] = hj_s[lane][k];
    const int j = j0 + lane;
#pragma unroll 4
    for (int ii = w * 16; ii < w * 16 + 16; ii++) {
        float acc = 0.0f;
#pragma unroll
        for (int k = 0; k < 32; k++) {
            acc += fabsf(hi_s[ii * 32 + k] - hj[k]);
        }
        out[(size_t)(i0 + ii) * N_NODES + j] = acc;
    }
}

extern "C" void kernel_launch(void* const* d_in, const int* in_sizes, int n_in,
                              void* d_out, int out_size, void* d_ws, size_t ws_size,
                              hipStream_t stream) {
    const float* x         = (const float*)d_in[0];
    const float* edge_attr = (const float*)d_in[1];
    const int*   edge_idx  = (const int*)d_in[2];
    const float* W1 = (const float*)d_in[3];
    const float* b1 = (const float*)d_in[4];
    const float* root1 = (const float*)d_in[5];
    const float* bias1 = (const float*)d_in[6];
    const float* W2 = (const float*)d_in[7];
    const float* b2 = (const float*)d_in[8];
    const float* root2 = (const float*)d_in[9];
    const float* bias2 = (const float*)d_in[10];
    const float* W3 = (const float*)d_in[11];
    const float* b3 = (const float*)d_in[12];
    const float* root3 = (const float*)d_in[13];
    const float* bias3 = (const float*)d_in[14];

    const int* src = edge_idx;            // row 0
    const int* dst = edge_idx + N_EDGES;  // row 1

    float* ws   = (float*)d_ws;
    float* cnt  = ws;
    float* sum1 = ws + N_NODES;
    float* sum2 = sum1 + N_NODES * C;
    float* sum3 = sum2 + N_NODES * C;
    float* h1   = sum3 + N_NODES * C;
    float* h2   = h1 + N_NODES * C;
    float* h3   = h2 + N_NODES * C;

    // zero cnt + sum1..sum3 (contiguous)
    hipMemsetAsync(d_ws, 0, (size_t)(N_NODES + 3 * N_NODES * C) * sizeof(float), stream);

    // Layer 1 (degree count fused)
    edge1_kernel<<<(N_EDGES * C) / 256, 256, 0, stream>>>(x, edge_attr, src, dst, W1, b1, sum1, cnt);
    node_kernel<1><<<(N_NODES * C) / 256, 256, 0, stream>>>(sum1, cnt, x, root1, bias1, h1);

    // Layer 2
    edge23_kernel<<<2048, 256, 0, stream>>>(h1, edge_attr, src, dst, W2, b2, sum2);
    node_kernel<C><<<(N_NODES * C) / 256, 256, 0, stream>>>(sum2, cnt, h1, root2, bias2, h2);

    // Layer 3
    edge23_kernel<<<2048, 256, 0, stream>>>(h2, edge_attr, src, dst, W3, b3, sum3);
    node_kernel<C><<<(N_NODES * C) / 256, 256, 0, stream>>>(sum3, cnt, h2, root3, bias3, h3);

    // CBT
    cbt_kernel<<<dim3(N_NODES / 64, N_NODES / 64), 256, 0, stream>>>(h3, (float*)d_out);
}